// Round 4
// baseline (555.761 us; speedup 1.0000x reference)
//
#include <hip/hip_runtime.h>

#define C 64
#define EPS 1e-5f
#define BUCK_CAP 2048
#define OVF_CAP 65536

typedef __attribute__((ext_vector_type(8))) short bf16x8;
typedef __attribute__((ext_vector_type(4))) float f32x4;

// ---- bf16 pack/unpack helpers (RNE) ---------------------------------------
static __device__ __forceinline__ unsigned int f2bf(float f) {
  unsigned int x = __float_as_uint(f);
  return (x + 0x7fffu + ((x >> 16) & 1u)) >> 16;
}
static __device__ __forceinline__ float bflo2f(unsigned int p) {
  return __uint_as_float(p << 16);
}
static __device__ __forceinline__ float bfhi2f(unsigned int p) {
  return __uint_as_float(p & 0xffff0000u);
}

// ---------------------------------------------------------------------------
// Prep: w1T[kout][c] = bf16(w1[c][kout]);  w2T[cout][k] = bf16(w2[k][cout])
// ---------------------------------------------------------------------------
__global__ __launch_bounds__(256) void prep_weights(
    const float* __restrict__ w1, const float* __restrict__ w2,
    unsigned short* __restrict__ w1T, unsigned short* __restrict__ w2T) {
  int idx = blockIdx.x * 256 + threadIdx.x;
  if (idx < 2 * C * C) {
    int k = idx >> 6, c = idx & 63;
    w1T[idx] = (unsigned short)f2bf(w1[c * 2 * C + k]);
  } else if (idx < 4 * C * C) {
    int j = idx - 2 * C * C;
    int c = j >> 7, k = j & 127;
    w2T[j] = (unsigned short)f2bf(w2[k * C + c]);
  }
}

// ---------------------------------------------------------------------------
// One-pass bucket binning. Bucket = recv>>6 (64 nodes). Block handles 4096
// edges: LDS histogram -> one global atomicAdd per touched bucket reserves a
// chunk -> LDS cursor assigns positions -> store 4B edge id. Positions >= cap
// go to the overflow list (handled exactly by fixup_kernel).
// ---------------------------------------------------------------------------
__global__ __launch_bounds__(256) void bin_kernel(
    const int* __restrict__ recv, int* __restrict__ region,
    int* __restrict__ bucketCnt, int* __restrict__ ovfList,
    int* __restrict__ ovfCnt, int n_edges, int nbuck) {
  __shared__ int hist[1024];  // nbuck <= 1024 (N <= 65536)
  int t = threadIdx.x;
  for (int i = t; i < 1024; i += 256) hist[i] = 0;
  __syncthreads();

  int base = blockIdx.x * 4096;
  int mybin[16];
#pragma unroll 16
  for (int j = 0; j < 16; j++) {
    int e = base + j * 256 + t;
    if (e < n_edges) {
      int b = recv[e] >> 6;
      mybin[j] = b;
      atomicAdd(&hist[b], 1);  // LDS atomic
    } else {
      mybin[j] = -1;
    }
  }
  __syncthreads();

  // reserve global chunks; hist[b] becomes this block's running cursor
  for (int i = t; i < nbuck; i += 256) {
    int c = hist[i];
    hist[i] = (c > 0) ? atomicAdd(&bucketCnt[i], c) : 0;
  }
  __syncthreads();

#pragma unroll 16
  for (int j = 0; j < 16; j++) {
    int b = mybin[j];
    if (b >= 0) {
      int e = base + j * 256 + t;
      int pos = atomicAdd(&hist[b], 1);  // LDS atomic, returns old
      if (pos < BUCK_CAP) {
        region[b * BUCK_CAP + pos] = e;
      } else {
        int o = atomicAdd(ovfCnt, 1);
        if (o < OVF_CAP) ovfList[o] = e;
      }
    }
  }
}

// ---------------------------------------------------------------------------
// Fused node kernel: LN -> GEMM1(bf16 MFMA) -> silu -> GEMM2 -> *vln -> D16.
// Block = 256 threads (4 waves), 64 nodes/block.
// ---------------------------------------------------------------------------
__global__ __launch_bounds__(256, 2) void node_kernel(
    const float* __restrict__ x, const float* __restrict__ vec,
    const float* __restrict__ ln_scale, const float* __restrict__ ln_bias,
    const float* __restrict__ vln_w,
    const unsigned short* __restrict__ w1T, const float* __restrict__ b1,
    const unsigned short* __restrict__ w2T, const float* __restrict__ b2,
    uint2* __restrict__ D16, int n_nodes) {
  __shared__ unsigned short An[64 * 72];
  __shared__ unsigned short Ss[64 * 136];
  __shared__ unsigned short W1s[128 * 72];
  __shared__ unsigned short W2s[64 * 136];

  const int t = threadIdx.x;
  const int lane = t & 63;
  const int wave = t >> 6;
  const int l15 = lane & 15;
  const int q = lane >> 4;

  {
    int r1 = t >> 1, h2 = t & 1;
    const uint4* s1 = (const uint4*)(w1T + r1 * 64 + h2 * 32);
    uint4* d1 = (uint4*)(W1s + r1 * 72 + h2 * 32);
    d1[0] = s1[0]; d1[1] = s1[1]; d1[2] = s1[2]; d1[3] = s1[3];
    int r2 = t >> 2, qd = t & 3;
    const uint4* s2 = (const uint4*)(w2T + r2 * 128 + qd * 32);
    uint4* d2 = (uint4*)(W2s + r2 * 136 + qd * 32);
    d2[0] = s2[0]; d2[1] = s2[1]; d2[2] = s2[2]; d2[3] = s2[3];
  }

  {
    int rowl = t >> 2;
    int part = t & 3;
    int node = blockIdx.x * 64 + rowl;
    int nc = node < n_nodes ? node : n_nodes - 1;
    const float* xp = x + (size_t)nc * C + part * 16;
    float xv[16];
    float s = 0.f;
#pragma unroll
    for (int i = 0; i < 4; i++) {
      float4 v = *(const float4*)(xp + i * 4);
      xv[i * 4 + 0] = v.x; xv[i * 4 + 1] = v.y;
      xv[i * 4 + 2] = v.z; xv[i * 4 + 3] = v.w;
      s += v.x + v.y + v.z + v.w;
    }
    s += __shfl_xor(s, 1);
    s += __shfl_xor(s, 2);
    float mean = s * (1.f / C);
    float vs = 0.f;
#pragma unroll
    for (int i = 0; i < 16; i++) {
      float d = xv[i] - mean;
      vs += d * d;
    }
    vs += __shfl_xor(vs, 1);
    vs += __shfl_xor(vs, 2);
    float rs = rsqrtf(vs * (1.f / C) + EPS);
    float ls[16], lb[16];
#pragma unroll
    for (int i = 0; i < 4; i++) {
      float4 a = *(const float4*)(ln_scale + part * 16 + i * 4);
      float4 b = *(const float4*)(ln_bias + part * 16 + i * 4);
      ls[i * 4 + 0] = a.x; ls[i * 4 + 1] = a.y; ls[i * 4 + 2] = a.z; ls[i * 4 + 3] = a.w;
      lb[i * 4 + 0] = b.x; lb[i * 4 + 1] = b.y; lb[i * 4 + 2] = b.z; lb[i * 4 + 3] = b.w;
    }
    unsigned int bp[8];
#pragma unroll
    for (int i = 0; i < 8; i++) {
      float e0 = (xv[2 * i] - mean) * rs * ls[2 * i] + lb[2 * i];
      float e1 = (xv[2 * i + 1] - mean) * rs * ls[2 * i + 1] + lb[2 * i + 1];
      bp[i] = f2bf(e0) | (f2bf(e1) << 16);
    }
    uint4* dst = (uint4*)(An + rowl * 72 + part * 16);
    uint4 p0 = {bp[0], bp[1], bp[2], bp[3]};
    uint4 p1 = {bp[4], bp[5], bp[6], bp[7]};
    dst[0] = p0;
    dst[1] = p1;
  }
  __syncthreads();

  const int Mbase = wave * 16;

  bf16x8 a0 = *(const bf16x8*)(An + (Mbase + l15) * 72 + q * 8);
  bf16x8 a1 = *(const bf16x8*)(An + (Mbase + l15) * 72 + 32 + q * 8);
  f32x4 acc1[8];
#pragma unroll
  for (int nt = 0; nt < 8; nt++) {
    const unsigned short* wb = W1s + (nt * 16 + l15) * 72 + q * 8;
    bf16x8 b0 = *(const bf16x8*)(wb);
    bf16x8 b1f = *(const bf16x8*)(wb + 32);
    f32x4 z = {0.f, 0.f, 0.f, 0.f};
    z = __builtin_amdgcn_mfma_f32_16x16x32_bf16(a0, b0, z, 0, 0, 0);
    z = __builtin_amdgcn_mfma_f32_16x16x32_bf16(a1, b1f, z, 0, 0, 0);
    acc1[nt] = z;
  }
#pragma unroll
  for (int nt = 0; nt < 8; nt++) {
    float bb = b1[nt * 16 + l15];
#pragma unroll
    for (int r = 0; r < 4; r++) {
      float h = acc1[nt][r] + bb;
      float sg = h / (1.f + __expf(-h));
      Ss[(Mbase + q * 4 + r) * 136 + nt * 16 + l15] = (unsigned short)f2bf(sg);
    }
  }
  __syncthreads();

  bf16x8 a2[4];
#pragma unroll
  for (int kt = 0; kt < 4; kt++)
    a2[kt] = *(const bf16x8*)(Ss + (Mbase + l15) * 136 + kt * 32 + q * 8);
  f32x4 acc2[4];
#pragma unroll
  for (int nt = 0; nt < 4; nt++) {
    f32x4 z = {0.f, 0.f, 0.f, 0.f};
#pragma unroll
    for (int kt = 0; kt < 4; kt++) {
      bf16x8 b = *(const bf16x8*)(W2s + (nt * 16 + l15) * 136 + kt * 32 + q * 8);
      z = __builtin_amdgcn_mfma_f32_16x16x32_bf16(a2[kt], b, z, 0, 0, 0);
    }
    acc2[nt] = z;
  }

#pragma unroll
  for (int nt = 0; nt < 4; nt++) {
    int cc = nt * 16 + l15;
    float bb = b2[cc];
    float vw = vln_w[cc];
#pragma unroll
    for (int r = 0; r < 4; r++) {
      int rl = Mbase + q * 4 + r;
      int nn = blockIdx.x * 64 + rl;
      if (nn < n_nodes) {
        float p = (acc2[nt][r] + bb) * vw;
        const float* vp = vec + (size_t)nn * (3 * C) + cc;
        float v0 = vp[0], v1 = vp[C], v2 = vp[2 * C];
        uint2 u;
        u.x = f2bf(p * v0) | (f2bf(p * v1) << 16);
        u.y = f2bf(p * v2);
        D16[(size_t)nn * C + cc] = u;
      }
    }
  }
}

// ---------------------------------------------------------------------------
// Accumulate per bucket (64 nodes). Receiver rows staged in LDS; fp32
// accumulators in LDS (atomicAdd -> ds_add); 4 edges in flight per wave;
// one coalesced store per node. No global atomics, no dx memset.
// ---------------------------------------------------------------------------
__global__ __launch_bounds__(256) void accum_bucket(
    const int* __restrict__ region, const int* __restrict__ bucketCnt,
    const int* __restrict__ senders, const int* __restrict__ receivers,
    const float* __restrict__ Mmat, const uint2* __restrict__ D2,
    float* __restrict__ dx, int n_nodes) {
  __shared__ float acc[64 * 64];   // 16 KB
  __shared__ uint2 rrow[64 * 64];  // 32 KB
  const int b = blockIdx.x;
  const int node0 = b * 64;
  const int t = threadIdx.x;
  const int lane = t & 63;
  const int wave = t >> 6;

  for (int i = t; i < 4096; i += 256) {
    acc[i] = 0.f;
    int row = i >> 6, ln = i & 63;
    int node = node0 + row;
    uint2 z; z.x = 0u; z.y = 0u;
    rrow[i] = (node < n_nodes) ? D2[(size_t)node * C + ln] : z;
  }
  __syncthreads();

  int cnt = bucketCnt[b];
  if (cnt > BUCK_CAP) cnt = BUCK_CAP;
  const int* reg = region + (size_t)b * BUCK_CAP;

  for (int i = wave * 4; i < cnt; i += 16) {
    int rem = cnt - i;  // >= 1
    // clamped indices: no load can leave the bucket region
    int i1 = (rem > 1) ? i + 1 : i;
    int i2 = (rem > 2) ? i + 2 : i;
    int i3 = (rem > 3) ? i + 3 : i;
    int e0 = reg[i], e1 = reg[i1], e2 = reg[i2], e3 = reg[i3];
    // independent index loads (4 chains in flight)
    int s0 = senders[e0], s1 = senders[e1], s2 = senders[e2], s3 = senders[e3];
    int r0 = receivers[e0] & 63, r1 = receivers[e1] & 63;
    int r2 = receivers[e2] & 63, r3 = receivers[e3] & 63;
    uint2 sv0 = D2[(size_t)s0 * C + lane];
    uint2 sv1 = D2[(size_t)s1 * C + lane];
    uint2 sv2 = D2[(size_t)s2 * C + lane];
    uint2 sv3 = D2[(size_t)s3 * C + lane];
    uint2 rv0 = rrow[r0 * 64 + lane];
    uint2 rv1 = rrow[r1 * 64 + lane];
    uint2 rv2 = rrow[r2 * 64 + lane];
    uint2 rv3 = rrow[r3 * 64 + lane];
    const float* M0 = Mmat + (size_t)__builtin_amdgcn_readfirstlane(e0) * 9;
    const float* M1 = Mmat + (size_t)__builtin_amdgcn_readfirstlane(e1) * 9;
    const float* M2 = Mmat + (size_t)__builtin_amdgcn_readfirstlane(e2) * 9;
    const float* M3 = Mmat + (size_t)__builtin_amdgcn_readfirstlane(e3) * 9;

#define EDGE_DOT(J, SV, RV, MP, RR)                                        \
  if (rem > (J)) {                                                         \
    float a0 = bflo2f(SV.x), a1 = bfhi2f(SV.x), a2 = bflo2f(SV.y);         \
    float c0 = bflo2f(RV.x), c1 = bfhi2f(RV.x), c2 = bflo2f(RV.y);         \
    float f0 = MP[0] * a0 + MP[1] * a1 + MP[2] * a2;                       \
    float f1 = MP[3] * a0 + MP[4] * a1 + MP[5] * a2;                       \
    float f2 = MP[6] * a0 + MP[7] * a1 + MP[8] * a2;                       \
    float dE = c0 * f0 + c1 * f1 + c2 * f2;                                \
    atomicAdd(&acc[(RR)*64 + lane], dE);                                   \
  }
    EDGE_DOT(0, sv0, rv0, M0, r0)
    EDGE_DOT(1, sv1, rv1, M1, r1)
    EDGE_DOT(2, sv2, rv2, M2, r2)
    EDGE_DOT(3, sv3, rv3, M3, r3)
#undef EDGE_DOT
  }
  __syncthreads();

  for (int i = t; i < 4096; i += 256) {
    int row = i >> 6, ln = i & 63;
    int node = node0 + row;
    if (node < n_nodes) dx[(size_t)node * C + ln] = acc[i];
  }
}

// ---------------------------------------------------------------------------
// Fixup: exact handling of (practically nonexistent) bucket overflow edges.
// One wave per overflow edge; global float atomics into dx.
// ---------------------------------------------------------------------------
__global__ __launch_bounds__(256) void fixup_kernel(
    const int* __restrict__ ovfList, const int* __restrict__ ovfCnt,
    const int* __restrict__ senders, const int* __restrict__ receivers,
    const float* __restrict__ Mmat, const uint2* __restrict__ D2,
    float* __restrict__ dx) {
  int nov = *ovfCnt;
  if (nov > OVF_CAP) nov = OVF_CAP;
  int lane = threadIdx.x & 63;
  for (int idx = blockIdx.x * 4 + (threadIdx.x >> 6); idx < nov;
       idx += gridDim.x * 4) {
    int e = ovfList[idx];
    int s = senders[e];
    int r = receivers[e];
    uint2 sv = D2[(size_t)s * C + lane];
    uint2 rv = D2[(size_t)r * C + lane];
    const float* M = Mmat + (size_t)e * 9;
    float a0 = bflo2f(sv.x), a1 = bfhi2f(sv.x), a2 = bflo2f(sv.y);
    float c0 = bflo2f(rv.x), c1 = bfhi2f(rv.x), c2 = bflo2f(rv.y);
    float f0 = M[0] * a0 + M[1] * a1 + M[2] * a2;
    float f1 = M[3] * a0 + M[4] * a1 + M[5] * a2;
    float f2 = M[6] * a0 + M[7] * a1 + M[8] * a2;
    float dE = c0 * f0 + c1 * f1 + c2 * f2;
    atomicAdd(dx + (size_t)r * C + lane, dE);
  }
}

// ---------------------------------------------------------------------------
extern "C" void kernel_launch(void* const* d_in, const int* in_sizes, int n_in,
                              void* d_out, int out_size, void* d_ws, size_t ws_size,
                              hipStream_t stream) {
  const float* x        = (const float*)d_in[0];
  const float* vec      = (const float*)d_in[1];
  const int*   senders  = (const int*)d_in[2];
  const int*   receivers= (const int*)d_in[3];
  const float* Mmat     = (const float*)d_in[4];
  const float* ln_scale = (const float*)d_in[5];
  const float* ln_bias  = (const float*)d_in[6];
  const float* vln_w    = (const float*)d_in[7];
  const float* w1       = (const float*)d_in[8];
  const float* b1       = (const float*)d_in[9];
  const float* w2       = (const float*)d_in[10];
  const float* b2       = (const float*)d_in[11];
  float* dx = (float*)d_out;

  int n_nodes = in_sizes[0] / C;   // 50000
  int n_edges = in_sizes[2];       // 800000
  int nbuck = (n_nodes + 63) >> 6; // 782

  // Workspace layout (total ~32.3 MB):
  //   [0]      w1T (16 KB) | w2T (16 KB)
  //   [32K]    D16 [N][C] uint2 = 25.6 MB
  //   then:    cnts (1024 bucketCnt + 1 ovfCnt ints), region (nbuck*2048 ints),
  //            ovfList (64K ints)
  unsigned short* w1T = (unsigned short*)d_ws;
  unsigned short* w2T = w1T + 2 * C * C;
  uint2* D16 = (uint2*)((char*)d_ws + 32768);
  char* p = (char*)d_ws + 32768 + (size_t)n_nodes * C * sizeof(uint2);
  p = (char*)(((size_t)p + 255) & ~(size_t)255);
  int* cnts    = (int*)p;  p += (1024 + 1) * 4;
  p = (char*)(((size_t)p + 255) & ~(size_t)255);
  int* region  = (int*)p;  p += (size_t)nbuck * BUCK_CAP * 4;
  int* ovfList = (int*)p;
  int* bucketCnt = cnts;
  int* ovfCnt = cnts + 1024;

  prep_weights<<<64, 256, 0, stream>>>(w1, w2, w1T, w2T);

  hipMemsetAsync(cnts, 0, (1024 + 1) * sizeof(int), stream);
  bin_kernel<<<(n_edges + 4095) / 4096, 256, 0, stream>>>(
      receivers, region, bucketCnt, ovfList, ovfCnt, n_edges, nbuck);

  node_kernel<<<(n_nodes + 63) / 64, 256, 0, stream>>>(
      x, vec, ln_scale, ln_bias, vln_w, w1T, b1, w2T, b2, D16, n_nodes);

  accum_bucket<<<nbuck, 256, 0, stream>>>(
      region, bucketCnt, senders, receivers, Mmat, D16, dx, n_nodes);

  fixup_kernel<<<128, 256, 0, stream>>>(
      ovfList, ovfCnt, senders, receivers, Mmat, D16, dx);
}

// Round 5
// 301.781 us; speedup vs baseline: 1.8416x; 1.8416x over previous
//
#include <hip/hip_runtime.h>

#define C 64
#define EPS 1e-5f
#define BUCK_CAP 1536
#define OVF_CAP 65536
#define SMASK 0x03ffffffu

typedef __attribute__((ext_vector_type(8))) short bf16x8;
typedef __attribute__((ext_vector_type(4))) float f32x4;

// ---- bf16 pack/unpack helpers (RNE) ---------------------------------------
static __device__ __forceinline__ unsigned int f2bf(float f) {
  unsigned int x = __float_as_uint(f);
  return (x + 0x7fffu + ((x >> 16) & 1u)) >> 16;
}
static __device__ __forceinline__ float bflo2f(unsigned int p) {
  return __uint_as_float(p << 16);
}
static __device__ __forceinline__ float bfhi2f(unsigned int p) {
  return __uint_as_float(p & 0xffff0000u);
}

// ---------------------------------------------------------------------------
// Prep: w1T[kout][c] = bf16(w1[c][kout]);  w2T[cout][k] = bf16(w2[k][cout])
// ---------------------------------------------------------------------------
__global__ __launch_bounds__(256) void prep_weights(
    const float* __restrict__ w1, const float* __restrict__ w2,
    unsigned short* __restrict__ w1T, unsigned short* __restrict__ w2T) {
  int idx = blockIdx.x * 256 + threadIdx.x;
  if (idx < 2 * C * C) {
    int k = idx >> 6, c = idx & 63;
    w1T[idx] = (unsigned short)f2bf(w1[c * 2 * C + k]);
  } else if (idx < 4 * C * C) {
    int j = idx - 2 * C * C;
    int c = j >> 7, k = j & 127;
    w2T[j] = (unsigned short)f2bf(w2[k * C + c]);
  }
}

// ---------------------------------------------------------------------------
// Bucket binning. Bucket = recv>>6. Record = {sender | (recv&63)<<26, edge}.
// LDS histogram -> one global atomicAdd per (block,bucket) chunk reservation
// -> LDS-cursor scatter of 8B records. Overflow -> exact fixup list.
// ---------------------------------------------------------------------------
__global__ __launch_bounds__(256) void bin_kernel(
    const int* __restrict__ recv, const int* __restrict__ send,
    uint2* __restrict__ region, int* __restrict__ bucketCnt,
    int* __restrict__ ovfList, int* __restrict__ ovfCnt,
    int n_edges, int nbuck) {
  __shared__ int hist[1024];  // nbuck <= 1024
  int t = threadIdx.x;
  for (int i = t; i < 1024; i += 256) hist[i] = 0;
  __syncthreads();

  int base = blockIdx.x * 4096;
  int myrecv[16], mysend[16];
#pragma unroll 16
  for (int j = 0; j < 16; j++) {
    int e = base + j * 256 + t;
    if (e < n_edges) {
      int r = recv[e];
      myrecv[j] = r;
      mysend[j] = send[e];
      atomicAdd(&hist[r >> 6], 1);  // LDS atomic
    } else {
      myrecv[j] = -1;
      mysend[j] = 0;
    }
  }
  __syncthreads();

  // reserve global chunks; hist[b] becomes this block's running cursor
  for (int i = t; i < nbuck; i += 256) {
    int c = hist[i];
    hist[i] = (c > 0) ? atomicAdd(&bucketCnt[i], c) : 0;
  }
  __syncthreads();

#pragma unroll 16
  for (int j = 0; j < 16; j++) {
    int r = myrecv[j];
    if (r >= 0) {
      int e = base + j * 256 + t;
      int b = r >> 6;
      int pos = atomicAdd(&hist[b], 1);  // LDS atomic
      if (pos < BUCK_CAP) {
        uint2 rec;
        rec.x = (unsigned)mysend[j] | ((unsigned)(r & 63) << 26);
        rec.y = (unsigned)e;
        region[(size_t)b * BUCK_CAP + pos] = rec;
      } else {
        int o = atomicAdd(ovfCnt, 1);
        if (o < OVF_CAP) ovfList[o] = e;
      }
    }
  }
}

// ---------------------------------------------------------------------------
// Per-bucket in-place counting sort by r6 (64 bins) + per-node [beg,end).
// ---------------------------------------------------------------------------
__global__ __launch_bounds__(256) void sort_kernel(
    uint2* __restrict__ region, const int* __restrict__ bucketCnt,
    int* __restrict__ nodeBeg, int* __restrict__ nodeEnd, int n_nodes) {
  __shared__ uint2 buf[BUCK_CAP];  // 12 KB
  __shared__ int hist[64];
  __shared__ int off[64];
  int b = blockIdx.x;
  int t = threadIdx.x;
  int cnt = bucketCnt[b];
  if (cnt > BUCK_CAP) cnt = BUCK_CAP;
  uint2* reg = region + (size_t)b * BUCK_CAP;

  if (t < 64) hist[t] = 0;
  __syncthreads();
  for (int i = t; i < cnt; i += 256) {
    uint2 r = reg[i];
    buf[i] = r;
    atomicAdd(&hist[r.x >> 26], 1);
  }
  __syncthreads();
  if (t == 0) {
    int run = 0;
#pragma unroll
    for (int j = 0; j < 64; j++) { off[j] = run; run += hist[j]; }
  }
  __syncthreads();
  for (int i = t; i < cnt; i += 256) {
    uint2 r = buf[i];
    int pos = atomicAdd(&off[r.x >> 26], 1);
    reg[pos] = r;
  }
  __syncthreads();
  if (t < 64) {
    int node = b * 64 + t;
    if (node < n_nodes) {
      int end = off[t];  // start + count after scatter
      nodeBeg[node] = b * BUCK_CAP + (end - hist[t]);
      nodeEnd[node] = b * BUCK_CAP + end;
    }
  }
}

// ---------------------------------------------------------------------------
// Fused node kernel: LN -> GEMM1(bf16 MFMA) -> silu -> GEMM2 -> *vln -> D16.
// (unchanged)
// ---------------------------------------------------------------------------
__global__ __launch_bounds__(256, 2) void node_kernel(
    const float* __restrict__ x, const float* __restrict__ vec,
    const float* __restrict__ ln_scale, const float* __restrict__ ln_bias,
    const float* __restrict__ vln_w,
    const unsigned short* __restrict__ w1T, const float* __restrict__ b1,
    const unsigned short* __restrict__ w2T, const float* __restrict__ b2,
    uint2* __restrict__ D16, int n_nodes) {
  __shared__ unsigned short An[64 * 72];
  __shared__ unsigned short Ss[64 * 136];
  __shared__ unsigned short W1s[128 * 72];
  __shared__ unsigned short W2s[64 * 136];

  const int t = threadIdx.x;
  const int lane = t & 63;
  const int wave = t >> 6;
  const int l15 = lane & 15;
  const int q = lane >> 4;

  {
    int r1 = t >> 1, h2 = t & 1;
    const uint4* s1 = (const uint4*)(w1T + r1 * 64 + h2 * 32);
    uint4* d1 = (uint4*)(W1s + r1 * 72 + h2 * 32);
    d1[0] = s1[0]; d1[1] = s1[1]; d1[2] = s1[2]; d1[3] = s1[3];
    int r2 = t >> 2, qd = t & 3;
    const uint4* s2 = (const uint4*)(w2T + r2 * 128 + qd * 32);
    uint4* d2 = (uint4*)(W2s + r2 * 136 + qd * 32);
    d2[0] = s2[0]; d2[1] = s2[1]; d2[2] = s2[2]; d2[3] = s2[3];
  }

  {
    int rowl = t >> 2;
    int part = t & 3;
    int node = blockIdx.x * 64 + rowl;
    int nc = node < n_nodes ? node : n_nodes - 1;
    const float* xp = x + (size_t)nc * C + part * 16;
    float xv[16];
    float s = 0.f;
#pragma unroll
    for (int i = 0; i < 4; i++) {
      float4 v = *(const float4*)(xp + i * 4);
      xv[i * 4 + 0] = v.x; xv[i * 4 + 1] = v.y;
      xv[i * 4 + 2] = v.z; xv[i * 4 + 3] = v.w;
      s += v.x + v.y + v.z + v.w;
    }
    s += __shfl_xor(s, 1);
    s += __shfl_xor(s, 2);
    float mean = s * (1.f / C);
    float vs = 0.f;
#pragma unroll
    for (int i = 0; i < 16; i++) {
      float d = xv[i] - mean;
      vs += d * d;
    }
    vs += __shfl_xor(vs, 1);
    vs += __shfl_xor(vs, 2);
    float rs = rsqrtf(vs * (1.f / C) + EPS);
    float ls[16], lb[16];
#pragma unroll
    for (int i = 0; i < 4; i++) {
      float4 a = *(const float4*)(ln_scale + part * 16 + i * 4);
      float4 b = *(const float4*)(ln_bias + part * 16 + i * 4);
      ls[i * 4 + 0] = a.x; ls[i * 4 + 1] = a.y; ls[i * 4 + 2] = a.z; ls[i * 4 + 3] = a.w;
      lb[i * 4 + 0] = b.x; lb[i * 4 + 1] = b.y; lb[i * 4 + 2] = b.z; lb[i * 4 + 3] = b.w;
    }
    unsigned int bp[8];
#pragma unroll
    for (int i = 0; i < 8; i++) {
      float e0 = (xv[2 * i] - mean) * rs * ls[2 * i] + lb[2 * i];
      float e1 = (xv[2 * i + 1] - mean) * rs * ls[2 * i + 1] + lb[2 * i + 1];
      bp[i] = f2bf(e0) | (f2bf(e1) << 16);
    }
    uint4* dst = (uint4*)(An + rowl * 72 + part * 16);
    uint4 p0 = {bp[0], bp[1], bp[2], bp[3]};
    uint4 p1 = {bp[4], bp[5], bp[6], bp[7]};
    dst[0] = p0;
    dst[1] = p1;
  }
  __syncthreads();

  const int Mbase = wave * 16;

  bf16x8 a0 = *(const bf16x8*)(An + (Mbase + l15) * 72 + q * 8);
  bf16x8 a1 = *(const bf16x8*)(An + (Mbase + l15) * 72 + 32 + q * 8);
  f32x4 acc1[8];
#pragma unroll
  for (int nt = 0; nt < 8; nt++) {
    const unsigned short* wb = W1s + (nt * 16 + l15) * 72 + q * 8;
    bf16x8 b0 = *(const bf16x8*)(wb);
    bf16x8 b1f = *(const bf16x8*)(wb + 32);
    f32x4 z = {0.f, 0.f, 0.f, 0.f};
    z = __builtin_amdgcn_mfma_f32_16x16x32_bf16(a0, b0, z, 0, 0, 0);
    z = __builtin_amdgcn_mfma_f32_16x16x32_bf16(a1, b1f, z, 0, 0, 0);
    acc1[nt] = z;
  }
#pragma unroll
  for (int nt = 0; nt < 8; nt++) {
    float bb = b1[nt * 16 + l15];
#pragma unroll
    for (int r = 0; r < 4; r++) {
      float h = acc1[nt][r] + bb;
      float sg = h / (1.f + __expf(-h));
      Ss[(Mbase + q * 4 + r) * 136 + nt * 16 + l15] = (unsigned short)f2bf(sg);
    }
  }
  __syncthreads();

  bf16x8 a2[4];
#pragma unroll
  for (int kt = 0; kt < 4; kt++)
    a2[kt] = *(const bf16x8*)(Ss + (Mbase + l15) * 136 + kt * 32 + q * 8);
  f32x4 acc2[4];
#pragma unroll
  for (int nt = 0; nt < 4; nt++) {
    f32x4 z = {0.f, 0.f, 0.f, 0.f};
#pragma unroll
    for (int kt = 0; kt < 4; kt++) {
      bf16x8 b = *(const bf16x8*)(W2s + (nt * 16 + l15) * 136 + kt * 32 + q * 8);
      z = __builtin_amdgcn_mfma_f32_16x16x32_bf16(a2[kt], b, z, 0, 0, 0);
    }
    acc2[nt] = z;
  }

#pragma unroll
  for (int nt = 0; nt < 4; nt++) {
    int cc = nt * 16 + l15;
    float bb = b2[cc];
    float vw = vln_w[cc];
#pragma unroll
    for (int r = 0; r < 4; r++) {
      int rl = Mbase + q * 4 + r;
      int nn = blockIdx.x * 64 + rl;
      if (nn < n_nodes) {
        float p = (acc2[nt][r] + bb) * vw;
        const float* vp = vec + (size_t)nn * (3 * C) + cc;
        float v0 = vp[0], v1 = vp[C], v2 = vp[2 * C];
        uint2 u;
        u.x = f2bf(p * v0) | (f2bf(p * v1) << 16);
        u.y = f2bf(p * v2);
        D16[(size_t)nn * C + cc] = u;
      }
    }
  }
}

// ---------------------------------------------------------------------------
// Accumulate: one wave per receiver node over its sorted record stream.
// 4-slot software pipeline: record (uniform load), sender D-row gather, and
// the 9 M floats are all prefetched 4 edges ahead. One plain store per node.
// ---------------------------------------------------------------------------
__global__ __launch_bounds__(256) void accum_node(
    const uint2* __restrict__ region, const int* __restrict__ nodeBeg,
    const int* __restrict__ nodeEnd, const float* __restrict__ Mmat,
    const uint2* __restrict__ D2, float* __restrict__ dx, int n_nodes) {
  int wid = threadIdx.x >> 6;
  int lane = threadIdx.x & 63;
  int n = blockIdx.x * 4 + wid;
  if (n >= n_nodes) return;

  int beg = nodeBeg[n];
  int end = nodeEnd[n];

  uint2 dr = D2[(size_t)n * C + lane];
  float r0 = bflo2f(dr.x), r1 = bfhi2f(dr.x), r2 = bflo2f(dr.y);
  float acc = 0.f;

  if (beg < end) {
    const int last = end - 1;
    uint2 svA, svB, svC, svD;
    float mA[9], mB[9], mC[9], mD[9];

#define LOADSLOT(SV, MM, IDX)                                                \
  {                                                                          \
    uint2 rec_ = region[(IDX)];                                              \
    SV = D2[(size_t)(rec_.x & SMASK) * C + lane];                            \
    const float* Mp_ =                                                       \
        Mmat + (size_t)__builtin_amdgcn_readfirstlane((int)rec_.y) * 9;      \
    _Pragma("unroll") for (int j_ = 0; j_ < 9; j_++) MM[j_] = Mp_[j_];       \
  }

#define COMPUTE(SV, MM)                                                      \
  {                                                                          \
    float a0 = bflo2f(SV.x), a1 = bfhi2f(SV.x), a2 = bflo2f(SV.y);           \
    float f0 = MM[0] * a0 + MM[1] * a1 + MM[2] * a2;                         \
    float f1 = MM[3] * a0 + MM[4] * a1 + MM[5] * a2;                         \
    float f2 = MM[6] * a0 + MM[7] * a1 + MM[8] * a2;                         \
    acc += r0 * f0 + r1 * f1 + r2 * f2;                                      \
  }

    int i1 = (beg + 1 > last) ? last : beg + 1;
    int i2 = (beg + 2 > last) ? last : beg + 2;
    int i3 = (beg + 3 > last) ? last : beg + 3;
    LOADSLOT(svA, mA, beg)
    LOADSLOT(svB, mB, i1)
    LOADSLOT(svC, mC, i2)
    LOADSLOT(svD, mD, i3)

    for (int e = beg; e <= last; e += 4) {
#define STAGE(K, SV, MM)                                                     \
  if (e + (K) <= last) {                                                     \
    COMPUTE(SV, MM)                                                          \
    int nx = e + (K) + 4;                                                    \
    if (nx <= last) LOADSLOT(SV, MM, nx)                                     \
  }
      STAGE(0, svA, mA)
      STAGE(1, svB, mB)
      STAGE(2, svC, mC)
      STAGE(3, svD, mD)
#undef STAGE
    }
#undef LOADSLOT
#undef COMPUTE
  }
  dx[(size_t)n * C + lane] = acc;
}

// ---------------------------------------------------------------------------
// Fixup: exact handling of (practically nonexistent) bucket overflow edges.
// ---------------------------------------------------------------------------
__global__ __launch_bounds__(256) void fixup_kernel(
    const int* __restrict__ ovfList, const int* __restrict__ ovfCnt,
    const int* __restrict__ senders, const int* __restrict__ receivers,
    const float* __restrict__ Mmat, const uint2* __restrict__ D2,
    float* __restrict__ dx) {
  int nov = *ovfCnt;
  if (nov > OVF_CAP) nov = OVF_CAP;
  int lane = threadIdx.x & 63;
  for (int idx = blockIdx.x * 4 + (threadIdx.x >> 6); idx < nov;
       idx += gridDim.x * 4) {
    int e = ovfList[idx];
    int s = senders[e];
    int r = receivers[e];
    uint2 sv = D2[(size_t)s * C + lane];
    uint2 rv = D2[(size_t)r * C + lane];
    const float* M = Mmat + (size_t)e * 9;
    float a0 = bflo2f(sv.x), a1 = bfhi2f(sv.x), a2 = bflo2f(sv.y);
    float c0 = bflo2f(rv.x), c1 = bfhi2f(rv.x), c2 = bflo2f(rv.y);
    float f0 = M[0] * a0 + M[1] * a1 + M[2] * a2;
    float f1 = M[3] * a0 + M[4] * a1 + M[5] * a2;
    float f2 = M[6] * a0 + M[7] * a1 + M[8] * a2;
    float dE = c0 * f0 + c1 * f1 + c2 * f2;
    atomicAdd(dx + (size_t)r * C + lane, dE);
  }
}

// ---------------------------------------------------------------------------
extern "C" void kernel_launch(void* const* d_in, const int* in_sizes, int n_in,
                              void* d_out, int out_size, void* d_ws, size_t ws_size,
                              hipStream_t stream) {
  const float* x        = (const float*)d_in[0];
  const float* vec      = (const float*)d_in[1];
  const int*   senders  = (const int*)d_in[2];
  const int*   receivers= (const int*)d_in[3];
  const float* Mmat     = (const float*)d_in[4];
  const float* ln_scale = (const float*)d_in[5];
  const float* ln_bias  = (const float*)d_in[6];
  const float* vln_w    = (const float*)d_in[7];
  const float* w1       = (const float*)d_in[8];
  const float* b1       = (const float*)d_in[9];
  const float* w2       = (const float*)d_in[10];
  const float* b2       = (const float*)d_in[11];
  float* dx = (float*)d_out;

  int n_nodes = in_sizes[0] / C;   // 50000
  int n_edges = in_sizes[2];       // 800000
  int nbuck = (n_nodes + 63) >> 6; // 782

  // Workspace layout (~36 MB):
  //   w1T|w2T (32 KB), D16 (25.6 MB), cnts (1025 ints),
  //   region (nbuck*1536 uint2 = 9.6 MB), nodeBeg/nodeEnd (N ints each),
  //   ovfList (64K ints)
  unsigned short* w1T = (unsigned short*)d_ws;
  unsigned short* w2T = w1T + 2 * C * C;
  uint2* D16 = (uint2*)((char*)d_ws + 32768);
  char* p = (char*)d_ws + 32768 + (size_t)n_nodes * C * sizeof(uint2);
  p = (char*)(((size_t)p + 255) & ~(size_t)255);
  int* cnts    = (int*)p;  p += (1024 + 1) * 4;
  p = (char*)(((size_t)p + 255) & ~(size_t)255);
  uint2* region = (uint2*)p;  p += (size_t)nbuck * BUCK_CAP * 8;
  int* nodeBeg = (int*)p;     p += (size_t)n_nodes * 4;
  int* nodeEnd = (int*)p;     p += (size_t)n_nodes * 4;
  int* ovfList = (int*)p;
  int* bucketCnt = cnts;
  int* ovfCnt = cnts + 1024;

  prep_weights<<<64, 256, 0, stream>>>(w1, w2, w1T, w2T);

  hipMemsetAsync(cnts, 0, (1024 + 1) * sizeof(int), stream);
  bin_kernel<<<(n_edges + 4095) / 4096, 256, 0, stream>>>(
      receivers, senders, region, bucketCnt, ovfList, ovfCnt, n_edges, nbuck);

  sort_kernel<<<nbuck, 256, 0, stream>>>(
      region, bucketCnt, nodeBeg, nodeEnd, n_nodes);

  node_kernel<<<(n_nodes + 63) / 64, 256, 0, stream>>>(
      x, vec, ln_scale, ln_bias, vln_w, w1T, b1, w2T, b2, D16, n_nodes);

  accum_node<<<(n_nodes + 3) / 4, 256, 0, stream>>>(
      region, nodeBeg, nodeEnd, Mmat, D16, dx, n_nodes);

  fixup_kernel<<<128, 256, 0, stream>>>(
      ovfList, ovfCnt, senders, receivers, Mmat, D16, dx);
}

// Round 6
// 269.445 us; speedup vs baseline: 2.0626x; 1.1200x over previous
//
#include <hip/hip_runtime.h>

#define C 64
#define EPS 1e-5f
#define BUCK_CAP 1536
#define OVF_CAP 65536
#define SMASK 0x03ffffffu

typedef __attribute__((ext_vector_type(8))) short bf16x8;
typedef __attribute__((ext_vector_type(4))) float f32x4;

// ---- bf16 pack/unpack helpers (RNE) ---------------------------------------
static __device__ __forceinline__ unsigned int f2bf(float f) {
  unsigned int x = __float_as_uint(f);
  return (x + 0x7fffu + ((x >> 16) & 1u)) >> 16;
}
static __device__ __forceinline__ float bflo2f(unsigned int p) {
  return __uint_as_float(p << 16);
}
static __device__ __forceinline__ float bfhi2f(unsigned int p) {
  return __uint_as_float(p & 0xffff0000u);
}

// ---------------------------------------------------------------------------
// Prep: w1T[kout][c] = bf16(w1[c][kout]);  w2T[cout][k] = bf16(w2[k][cout])
// ---------------------------------------------------------------------------
__global__ __launch_bounds__(256) void prep_weights(
    const float* __restrict__ w1, const float* __restrict__ w2,
    unsigned short* __restrict__ w1T, unsigned short* __restrict__ w2T) {
  int idx = blockIdx.x * 256 + threadIdx.x;
  if (idx < 2 * C * C) {
    int k = idx >> 6, c = idx & 63;
    w1T[idx] = (unsigned short)f2bf(w1[c * 2 * C + k]);
  } else if (idx < 4 * C * C) {
    int j = idx - 2 * C * C;
    int c = j >> 7, k = j & 127;
    w2T[j] = (unsigned short)f2bf(w2[k * C + c]);
  }
}

// ---------------------------------------------------------------------------
// Bucket binning. Bucket = recv>>6. Record = {sender | (recv&63)<<26, edge}.
// ---------------------------------------------------------------------------
__global__ __launch_bounds__(256) void bin_kernel(
    const int* __restrict__ recv, const int* __restrict__ send,
    uint2* __restrict__ region, int* __restrict__ bucketCnt,
    int* __restrict__ ovfList, int* __restrict__ ovfCnt,
    int n_edges, int nbuck) {
  __shared__ int hist[1024];  // nbuck <= 1024
  int t = threadIdx.x;
  for (int i = t; i < 1024; i += 256) hist[i] = 0;
  __syncthreads();

  int base = blockIdx.x * 4096;
  int myrecv[16], mysend[16];
#pragma unroll 16
  for (int j = 0; j < 16; j++) {
    int e = base + j * 256 + t;
    if (e < n_edges) {
      int r = recv[e];
      myrecv[j] = r;
      mysend[j] = send[e];
      atomicAdd(&hist[r >> 6], 1);  // LDS atomic
    } else {
      myrecv[j] = -1;
      mysend[j] = 0;
    }
  }
  __syncthreads();

  for (int i = t; i < nbuck; i += 256) {
    int c = hist[i];
    hist[i] = (c > 0) ? atomicAdd(&bucketCnt[i], c) : 0;
  }
  __syncthreads();

#pragma unroll 16
  for (int j = 0; j < 16; j++) {
    int r = myrecv[j];
    if (r >= 0) {
      int e = base + j * 256 + t;
      int b = r >> 6;
      int pos = atomicAdd(&hist[b], 1);  // LDS atomic
      if (pos < BUCK_CAP) {
        uint2 rec;
        rec.x = (unsigned)mysend[j] | ((unsigned)(r & 63) << 26);
        rec.y = (unsigned)e;
        region[(size_t)b * BUCK_CAP + pos] = rec;
      } else {
        int o = atomicAdd(ovfCnt, 1);
        if (o < OVF_CAP) ovfList[o] = e;
      }
    }
  }
}

// ---------------------------------------------------------------------------
// Per-bucket in-place counting sort by r6 (64 bins) + per-node [beg,end).
// ---------------------------------------------------------------------------
__global__ __launch_bounds__(256) void sort_kernel(
    uint2* __restrict__ region, const int* __restrict__ bucketCnt,
    int* __restrict__ nodeBeg, int* __restrict__ nodeEnd, int n_nodes) {
  __shared__ uint2 buf[BUCK_CAP];  // 12 KB
  __shared__ int hist[64];
  __shared__ int off[64];
  int b = blockIdx.x;
  int t = threadIdx.x;
  int cnt = bucketCnt[b];
  if (cnt > BUCK_CAP) cnt = BUCK_CAP;
  uint2* reg = region + (size_t)b * BUCK_CAP;

  if (t < 64) hist[t] = 0;
  __syncthreads();
  for (int i = t; i < cnt; i += 256) {
    uint2 r = reg[i];
    buf[i] = r;
    atomicAdd(&hist[r.x >> 26], 1);
  }
  __syncthreads();
  if (t == 0) {
    int run = 0;
#pragma unroll
    for (int j = 0; j < 64; j++) { off[j] = run; run += hist[j]; }
  }
  __syncthreads();
  for (int i = t; i < cnt; i += 256) {
    uint2 r = buf[i];
    int pos = atomicAdd(&off[r.x >> 26], 1);
    reg[pos] = r;
  }
  __syncthreads();
  if (t < 64) {
    int node = b * 64 + t;
    if (node < n_nodes) {
      int end = off[t];  // start + count after scatter
      nodeBeg[node] = b * BUCK_CAP + (end - hist[t]);
      nodeEnd[node] = b * BUCK_CAP + end;
    }
  }
}

// ---------------------------------------------------------------------------
// Fused node kernel v2: LN -> GEMM1 -> silu -> GEMM2 -> *vln -> D16.
// Weights read DIRECTLY from global (L2-resident, 48 KB total shared by all
// blocks) instead of per-block LDS staging: LDS 62.4 -> 26.6 KB, 2 -> 4+
// blocks/CU.  B-frag loads touch 1 KB contiguous regions (16 rows x 64B).
// ---------------------------------------------------------------------------
__global__ __launch_bounds__(256, 4) void node_kernel(
    const float* __restrict__ x, const float* __restrict__ vec,
    const float* __restrict__ ln_scale, const float* __restrict__ ln_bias,
    const float* __restrict__ vln_w,
    const unsigned short* __restrict__ w1T, const float* __restrict__ b1,
    const unsigned short* __restrict__ w2T, const float* __restrict__ b2,
    uint2* __restrict__ D16, int n_nodes) {
  __shared__ unsigned short An[64 * 72];   // x_norm bf16 [row][c], pitch 72
  __shared__ unsigned short Ss[64 * 136];  // silu(h) bf16 [row][k], pitch 136

  const int t = threadIdx.x;
  const int lane = t & 63;
  const int wave = t >> 6;
  const int l15 = lane & 15;
  const int q = lane >> 4;

  // ---- LayerNorm: 4 threads per row, 16 channels each ----
  {
    int rowl = t >> 2;
    int part = t & 3;
    int node = blockIdx.x * 64 + rowl;
    int nc = node < n_nodes ? node : n_nodes - 1;
    const float* xp = x + (size_t)nc * C + part * 16;
    float xv[16];
    float s = 0.f;
#pragma unroll
    for (int i = 0; i < 4; i++) {
      float4 v = *(const float4*)(xp + i * 4);
      xv[i * 4 + 0] = v.x; xv[i * 4 + 1] = v.y;
      xv[i * 4 + 2] = v.z; xv[i * 4 + 3] = v.w;
      s += v.x + v.y + v.z + v.w;
    }
    s += __shfl_xor(s, 1);
    s += __shfl_xor(s, 2);
    float mean = s * (1.f / C);
    float vs = 0.f;
#pragma unroll
    for (int i = 0; i < 16; i++) {
      float d = xv[i] - mean;
      vs += d * d;
    }
    vs += __shfl_xor(vs, 1);
    vs += __shfl_xor(vs, 2);
    float rs = rsqrtf(vs * (1.f / C) + EPS);
    float ls[16], lb[16];
#pragma unroll
    for (int i = 0; i < 4; i++) {
      float4 a = *(const float4*)(ln_scale + part * 16 + i * 4);
      float4 b = *(const float4*)(ln_bias + part * 16 + i * 4);
      ls[i * 4 + 0] = a.x; ls[i * 4 + 1] = a.y; ls[i * 4 + 2] = a.z; ls[i * 4 + 3] = a.w;
      lb[i * 4 + 0] = b.x; lb[i * 4 + 1] = b.y; lb[i * 4 + 2] = b.z; lb[i * 4 + 3] = b.w;
    }
    unsigned int bp[8];
#pragma unroll
    for (int i = 0; i < 8; i++) {
      float e0 = (xv[2 * i] - mean) * rs * ls[2 * i] + lb[2 * i];
      float e1 = (xv[2 * i + 1] - mean) * rs * ls[2 * i + 1] + lb[2 * i + 1];
      bp[i] = f2bf(e0) | (f2bf(e1) << 16);
    }
    uint4* dst = (uint4*)(An + rowl * 72 + part * 16);
    uint4 p0 = {bp[0], bp[1], bp[2], bp[3]};
    uint4 p1 = {bp[4], bp[5], bp[6], bp[7]};
    dst[0] = p0;
    dst[1] = p1;
  }
  __syncthreads();

  const int Mbase = wave * 16;

  // ---- GEMM1: h = x_norm @ w1  (M=16/wave, N=128, K=64); B from global ----
  bf16x8 a0 = *(const bf16x8*)(An + (Mbase + l15) * 72 + q * 8);
  bf16x8 a1 = *(const bf16x8*)(An + (Mbase + l15) * 72 + 32 + q * 8);
  f32x4 acc1[8];
#pragma unroll
  for (int nt = 0; nt < 8; nt++) {
    const unsigned short* wb = w1T + (nt * 16 + l15) * 64 + q * 8;
    bf16x8 b0 = *(const bf16x8*)(wb);
    bf16x8 b1f = *(const bf16x8*)(wb + 32);
    f32x4 z = {0.f, 0.f, 0.f, 0.f};
    z = __builtin_amdgcn_mfma_f32_16x16x32_bf16(a0, b0, z, 0, 0, 0);
    z = __builtin_amdgcn_mfma_f32_16x16x32_bf16(a1, b1f, z, 0, 0, 0);
    acc1[nt] = z;
  }
#pragma unroll
  for (int nt = 0; nt < 8; nt++) {
    float bb = b1[nt * 16 + l15];
#pragma unroll
    for (int r = 0; r < 4; r++) {
      float h = acc1[nt][r] + bb;
      float sg = h / (1.f + __expf(-h));
      Ss[(Mbase + q * 4 + r) * 136 + nt * 16 + l15] = (unsigned short)f2bf(sg);
    }
  }
  __syncthreads();

  // ---- GEMM2: p = s @ w2  (M=16/wave, N=64, K=128); B from global ----
  bf16x8 a2[4];
#pragma unroll
  for (int kt = 0; kt < 4; kt++)
    a2[kt] = *(const bf16x8*)(Ss + (Mbase + l15) * 136 + kt * 32 + q * 8);
  f32x4 acc2[4];
#pragma unroll
  for (int nt = 0; nt < 4; nt++) {
    f32x4 z = {0.f, 0.f, 0.f, 0.f};
#pragma unroll
    for (int kt = 0; kt < 4; kt++) {
      bf16x8 b = *(const bf16x8*)(w2T + (nt * 16 + l15) * 128 + kt * 32 + q * 8);
      z = __builtin_amdgcn_mfma_f32_16x16x32_bf16(a2[kt], b, z, 0, 0, 0);
    }
    acc2[nt] = z;
  }

  // ---- epilogue: p*vln_w, D = q*vec packed bf16 uint2 ----
#pragma unroll
  for (int nt = 0; nt < 4; nt++) {
    int cc = nt * 16 + l15;
    float bb = b2[cc];
    float vw = vln_w[cc];
#pragma unroll
    for (int r = 0; r < 4; r++) {
      int rl = Mbase + q * 4 + r;
      int nn = blockIdx.x * 64 + rl;
      if (nn < n_nodes) {
        float p = (acc2[nt][r] + bb) * vw;
        const float* vp = vec + (size_t)nn * (3 * C) + cc;
        float v0 = vp[0], v1 = vp[C], v2 = vp[2 * C];
        uint2 u;
        u.x = f2bf(p * v0) | (f2bf(p * v1) << 16);
        u.y = f2bf(p * v2);
        D16[(size_t)nn * C + cc] = u;
      }
    }
  }
}

// ---------------------------------------------------------------------------
// Accumulate v2: one wave per receiver node, 6-slot software pipeline.
// beg/end scalarized via readfirstlane -> record stream + M loads become
// scalar (SMEM) loads. One plain store per node.
// ---------------------------------------------------------------------------
__global__ __launch_bounds__(256) void accum_node(
    const uint2* __restrict__ region, const int* __restrict__ nodeBeg,
    const int* __restrict__ nodeEnd, const float* __restrict__ Mmat,
    const uint2* __restrict__ D2, float* __restrict__ dx, int n_nodes) {
  int wid = threadIdx.x >> 6;
  int lane = threadIdx.x & 63;
  int n = blockIdx.x * 4 + wid;
  if (n >= n_nodes) return;

  int beg = __builtin_amdgcn_readfirstlane(nodeBeg[n]);
  int end = __builtin_amdgcn_readfirstlane(nodeEnd[n]);

  uint2 dr = D2[(size_t)n * C + lane];
  float r0 = bflo2f(dr.x), r1 = bfhi2f(dr.x), r2 = bflo2f(dr.y);
  float acc = 0.f;

  if (beg < end) {
    const int last = end - 1;
    uint2 svA, svB, svC, svD, svE, svF;
    float mA[9], mB[9], mC[9], mD[9], mE[9], mF[9];

#define LOADSLOT(SV, MM, IDX)                                                \
  {                                                                          \
    uint2 rec_ = region[(IDX)];                                              \
    SV = D2[(size_t)(rec_.x & SMASK) * C + lane];                            \
    const float* Mp_ =                                                       \
        Mmat + (size_t)__builtin_amdgcn_readfirstlane((int)rec_.y) * 9;      \
    _Pragma("unroll") for (int j_ = 0; j_ < 9; j_++) MM[j_] = Mp_[j_];       \
  }

#define COMPUTE(SV, MM)                                                      \
  {                                                                          \
    float a0 = bflo2f(SV.x), a1 = bfhi2f(SV.x), a2 = bflo2f(SV.y);           \
    float f0 = MM[0] * a0 + MM[1] * a1 + MM[2] * a2;                         \
    float f1 = MM[3] * a0 + MM[4] * a1 + MM[5] * a2;                         \
    float f2 = MM[6] * a0 + MM[7] * a1 + MM[8] * a2;                         \
    acc += r0 * f0 + r1 * f1 + r2 * f2;                                      \
  }

    int i1 = (beg + 1 > last) ? last : beg + 1;
    int i2 = (beg + 2 > last) ? last : beg + 2;
    int i3 = (beg + 3 > last) ? last : beg + 3;
    int i4 = (beg + 4 > last) ? last : beg + 4;
    int i5 = (beg + 5 > last) ? last : beg + 5;
    LOADSLOT(svA, mA, beg)
    LOADSLOT(svB, mB, i1)
    LOADSLOT(svC, mC, i2)
    LOADSLOT(svD, mD, i3)
    LOADSLOT(svE, mE, i4)
    LOADSLOT(svF, mF, i5)

    for (int e = beg; e <= last; e += 6) {
#define STAGE(K, SV, MM)                                                     \
  if (e + (K) <= last) {                                                     \
    COMPUTE(SV, MM)                                                          \
    int nx = e + (K) + 6;                                                    \
    if (nx <= last) LOADSLOT(SV, MM, nx)                                     \
  }
      STAGE(0, svA, mA)
      STAGE(1, svB, mB)
      STAGE(2, svC, mC)
      STAGE(3, svD, mD)
      STAGE(4, svE, mE)
      STAGE(5, svF, mF)
#undef STAGE
    }
#undef LOADSLOT
#undef COMPUTE
  }
  dx[(size_t)n * C + lane] = acc;
}

// ---------------------------------------------------------------------------
// Fixup: exact handling of (practically nonexistent) bucket overflow edges.
// ---------------------------------------------------------------------------
__global__ __launch_bounds__(256) void fixup_kernel(
    const int* __restrict__ ovfList, const int* __restrict__ ovfCnt,
    const int* __restrict__ senders, const int* __restrict__ receivers,
    const float* __restrict__ Mmat, const uint2* __restrict__ D2,
    float* __restrict__ dx) {
  int nov = *ovfCnt;
  if (nov > OVF_CAP) nov = OVF_CAP;
  int lane = threadIdx.x & 63;
  for (int idx = blockIdx.x * 4 + (threadIdx.x >> 6); idx < nov;
       idx += gridDim.x * 4) {
    int e = ovfList[idx];
    int s = senders[e];
    int r = receivers[e];
    uint2 sv = D2[(size_t)s * C + lane];
    uint2 rv = D2[(size_t)r * C + lane];
    const float* M = Mmat + (size_t)e * 9;
    float a0 = bflo2f(sv.x), a1 = bfhi2f(sv.x), a2 = bflo2f(sv.y);
    float c0 = bflo2f(rv.x), c1 = bfhi2f(rv.x), c2 = bflo2f(rv.y);
    float f0 = M[0] * a0 + M[1] * a1 + M[2] * a2;
    float f1 = M[3] * a0 + M[4] * a1 + M[5] * a2;
    float f2 = M[6] * a0 + M[7] * a1 + M[8] * a2;
    float dE = c0 * f0 + c1 * f1 + c2 * f2;
    atomicAdd(dx + (size_t)r * C + lane, dE);
  }
}

// ---------------------------------------------------------------------------
extern "C" void kernel_launch(void* const* d_in, const int* in_sizes, int n_in,
                              void* d_out, int out_size, void* d_ws, size_t ws_size,
                              hipStream_t stream) {
  const float* x        = (const float*)d_in[0];
  const float* vec      = (const float*)d_in[1];
  const int*   senders  = (const int*)d_in[2];
  const int*   receivers= (const int*)d_in[3];
  const float* Mmat     = (const float*)d_in[4];
  const float* ln_scale = (const float*)d_in[5];
  const float* ln_bias  = (const float*)d_in[6];
  const float* vln_w    = (const float*)d_in[7];
  const float* w1       = (const float*)d_in[8];
  const float* b1       = (const float*)d_in[9];
  const float* w2       = (const float*)d_in[10];
  const float* b2       = (const float*)d_in[11];
  float* dx = (float*)d_out;

  int n_nodes = in_sizes[0] / C;   // 50000
  int n_edges = in_sizes[2];       // 800000
  int nbuck = (n_nodes + 63) >> 6; // 782

  // Workspace layout (~36 MB):
  //   w1T|w2T (32 KB), D16 (25.6 MB), cnts (1025 ints),
  //   region (nbuck*1536 uint2 = 9.6 MB), nodeBeg/nodeEnd (N ints each),
  //   ovfList (64K ints)
  unsigned short* w1T = (unsigned short*)d_ws;
  unsigned short* w2T = w1T + 2 * C * C;
  uint2* D16 = (uint2*)((char*)d_ws + 32768);
  char* p = (char*)d_ws + 32768 + (size_t)n_nodes * C * sizeof(uint2);
  p = (char*)(((size_t)p + 255) & ~(size_t)255);
  int* cnts    = (int*)p;  p += (1024 + 1) * 4;
  p = (char*)(((size_t)p + 255) & ~(size_t)255);
  uint2* region = (uint2*)p;  p += (size_t)nbuck * BUCK_CAP * 8;
  int* nodeBeg = (int*)p;     p += (size_t)n_nodes * 4;
  int* nodeEnd = (int*)p;     p += (size_t)n_nodes * 4;
  int* ovfList = (int*)p;
  int* bucketCnt = cnts;
  int* ovfCnt = cnts + 1024;

  prep_weights<<<64, 256, 0, stream>>>(w1, w2, w1T, w2T);

  hipMemsetAsync(cnts, 0, (1024 + 1) * sizeof(int), stream);
  bin_kernel<<<(n_edges + 4095) / 4096, 256, 0, stream>>>(
      receivers, senders, region, bucketCnt, ovfList, ovfCnt, n_edges, nbuck);

  sort_kernel<<<nbuck, 256, 0, stream>>>(
      region, bucketCnt, nodeBeg, nodeEnd, n_nodes);

  node_kernel<<<(n_nodes + 63) / 64, 256, 0, stream>>>(
      x, vec, ln_scale, ln_bias, vln_w, w1T, b1, w2T, b2, D16, n_nodes);

  accum_node<<<(n_nodes + 3) / 4, 256, 0, stream>>>(
      region, nodeBeg, nodeEnd, Mmat, D16, dx, n_nodes);

  fixup_kernel<<<128, 256, 0, stream>>>(
      ovfList, ovfCnt, senders, receivers, Mmat, D16, dx);
}